// Round 7
// baseline (2710.277 us; speedup 1.0000x reference)
//
#include <hip/hip_runtime.h>

#define Bsz 512
#define Tsz 64
#define Hsz 512
#define BH ((size_t)Bsz * Hsz)

typedef __attribute__((ext_vector_type(8))) short bf16x8;
typedef __attribute__((ext_vector_type(4))) float f32x4;

__device__ __forceinline__ unsigned short f2bf(float f) {
  union { float f; unsigned int u; } a; a.f = f;
  unsigned int u = a.u;
  unsigned int lsb = (u >> 16) & 1;
  u += 0x7fffu + lsb;   // round-to-nearest-even
  return (unsigned short)(u >> 16);
}

__device__ __forceinline__ void gload16(const void* g, void* l) {
  __builtin_amdgcn_global_load_lds(
      (const __attribute__((address_space(1))) unsigned int*)g,
      (__attribute__((address_space(3))) unsigned int*)l, 16, 0, 0);
}

__device__ __forceinline__ float sigm(float x) { return 1.f / (1.f + __expf(-x)); }
__device__ __forceinline__ float tanh_f(float x) { return 2.f / (1.f + __expf(-2.f * x)) - 1.f; }

// ---------------- converts ----------------
__global__ __launch_bounds__(256) void k_conv_x(const float* __restrict__ x,
                                                unsigned short* __restrict__ xbf) {
  int v = blockIdx.x * 256 + threadIdx.x;
  int e = v * 8;
  int i = e & 511;
  int t = (e >> 9) & 63;
  int b = e >> 15;
  float4 f0 = *(const float4*)(x + e);
  float4 f1 = *(const float4*)(x + e + 4);
  bf16x8 o;
  o[0] = (short)f2bf(f0.x); o[1] = (short)f2bf(f0.y);
  o[2] = (short)f2bf(f0.z); o[3] = (short)f2bf(f0.w);
  o[4] = (short)f2bf(f1.x); o[5] = (short)f2bf(f1.y);
  o[6] = (short)f2bf(f1.z); o[7] = (short)f2bf(f1.w);
  *(bf16x8*)(xbf + ((size_t)(t * 512 + b) << 9) + i) = o;
}

__global__ __launch_bounds__(256) void k_conv_w(
    const float* __restrict__ wihf, const float* __restrict__ whhf,
    const float* __restrict__ wihb, const float* __restrict__ whhb,
    const float* __restrict__ wlin,
    unsigned short* __restrict__ Wcat, unsigned short* __restrict__ wlinbf) {
  int v = blockIdx.x * 256 + threadIdx.x;
  const int nW = 2 * 16 * 128 * 128;
  if (v < nW) {
    int k8 = v & 127; int row = v >> 7;
    int c = row & 127, sl = (row >> 7) & 15, d = row >> 11;
    int g = c >> 5, hl = c & 31;
    int wr = g * 512 + sl * 32 + hl;
    int k = k8 * 8;
    const float* src;
    if (k < 512) src = (d ? wihb : wihf) + (size_t)wr * 512 + k;
    else         src = (d ? whhb : whhf) + (size_t)wr * 512 + (k - 512);
    float4 f0 = *(const float4*)src;
    float4 f1 = *(const float4*)(src + 4);
    bf16x8 o;
    o[0] = (short)f2bf(f0.x); o[1] = (short)f2bf(f0.y);
    o[2] = (short)f2bf(f0.z); o[3] = (short)f2bf(f0.w);
    o[4] = (short)f2bf(f1.x); o[5] = (short)f2bf(f1.y);
    o[6] = (short)f2bf(f1.z); o[7] = (short)f2bf(f1.w);
    *(bf16x8*)(Wcat + (size_t)row * 1024 + k) = o;
  } else {
    int v2 = v - nW;
    const float* src = wlin + (size_t)v2 * 8;
    float4 f0 = *(const float4*)src;
    float4 f1 = *(const float4*)(src + 4);
    bf16x8 o;
    o[0] = (short)f2bf(f0.x); o[1] = (short)f2bf(f0.y);
    o[2] = (short)f2bf(f0.z); o[3] = (short)f2bf(f0.w);
    o[4] = (short)f2bf(f1.x); o[5] = (short)f2bf(f1.y);
    o[6] = (short)f2bf(f1.z); o[7] = (short)f2bf(f1.w);
    *(bf16x8*)(wlinbf + (size_t)v2 * 8) = o;
  }
}

// ---------------- persistent LSTM: all 64 steps, one launch ----------------
// 256 blocks (1/CU): blockIdx = mt*32 + sl*2 + dir. Tile [64 batch][128 cols], K=1024.
// LDS: 5 chunk-bufs x 24KB = 120KB @0; sD f32[64][128] = 32KB @122880. Total 155648.
// Continuous pipeline over g = s*16+m (1024 chunks), stage depth 3, counted vmcnt(18).
// Group sync: 16 blocks sharing (mt,dir); monotonic counter bar[mt*2+dir]; step s waits >=16*s
// before staging its first h-chunk (m=5); release = threadfence + RELEASE atomicAdd.
__global__ __launch_bounds__(256) void k_lstm(
    const unsigned short* __restrict__ xbf, const unsigned short* __restrict__ h0,
    const unsigned short* __restrict__ Wcat,
    const float* __restrict__ biasf, const float* __restrict__ biasb,
    unsigned short* hsf, unsigned short* hsb, int* bar) {
  extern __shared__ char smem[];
  float* sD = (float*)(smem + 122880);
  const int tid = threadIdx.x;
  const int g32 = blockIdx.x & 31;
  const int mt  = blockIdx.x >> 5;
  const int dir = g32 & 1;
  const int sl  = g32 >> 1;
  const int b0  = mt * 64;

  const unsigned short* Wd = Wcat + (size_t)(dir * 16 + sl) * (128 * 1024);
  const float* bias = dir ? biasb : biasf;
  unsigned short* hs_my = dir ? hsb : hsf;
  int* mybar = bar + (mt * 2 + dir);

  const int lane = tid & 63;
  const int wv = tid >> 6;
  const int wr = wv >> 1, wc = wv & 1;
  const int l15 = lane & 15, l4 = lane >> 4;
  const int hl = tid & 31;
  const int r0 = tid >> 5;
  const int hcg = sl * 32 + hl;

  const float bi = bias[hcg], bff = bias[512 + hcg], bg = bias[1024 + hcg], bo = bias[1536 + hcg];

  float cv[8];
#pragma unroll
  for (int ii = 0; ii < 8; ++ii) cv[ii] = 0.f;

  const f32x4 z4 = {0.f, 0.f, 0.f, 0.f};
  f32x4 acc[2][4];
#pragma unroll
  for (int i = 0; i < 2; ++i)
#pragma unroll
    for (int j = 0; j < 4; ++j) acc[i][j] = z4;

  // stage global chunk gs (= ss*16+kc) into buf[gs%5]; 6 gload_lds per thread
  auto STAGE = [&](int gs) {
    int ss = gs >> 4, kc = gs & 15;
    char* buf = smem + (gs % 5) * 24576;
    const unsigned short* Asrc;
    if (kc < 8) {
      int t = dir ? 63 - ss : ss;
      Asrc = xbf + (size_t)t * BH;
    } else if (ss == 0) {
      Asrc = h0;
    } else {
      int tp = dir ? (64 - ss) : (ss - 1);
      Asrc = hs_my + (size_t)tp * BH;
    }
    const int koff = (kc & 7) * 64;
#pragma unroll
    for (int it = 0; it < 2; ++it) {
      int idx = it * 256 + tid;
      int row = idx >> 3, g = idx & 7;
      int sc = g ^ (row & 7);
      gload16(Asrc + (size_t)(b0 + row) * 512 + koff + sc * 8, buf + idx * 16);
    }
#pragma unroll
    for (int it = 0; it < 4; ++it) {
      int idx = it * 256 + tid;
      int row = idx >> 3, g = idx & 7;
      int sc = g ^ (row & 7);
      gload16(Wd + (size_t)row * 1024 + kc * 64 + sc * 8, buf + 8192 + idx * 16);
    }
  };

  // prologue: chunks 0,1,2 of step 0 (x-part, no sync needed)
  STAGE(0); STAGE(1); STAGE(2);

  for (int s = 0; s < 64; ++s) {
#pragma unroll 1
    for (int m = 0; m < 16; ++m) {
      const int g = s * 16 + m;
      char* cur = smem + (g % 5) * 24576;
      const int gs = g + 3;
      if (gs < 1024) {
        if ((gs & 15) == 8) {
          // about to stage first h-chunk of step ss=gs>>4: group barrier + acquire
          const int target = 16 * (gs >> 4);
          if (tid == 0) {
            while (__hip_atomic_load(mybar, __ATOMIC_RELAXED, __HIP_MEMORY_SCOPE_AGENT) < target)
              __builtin_amdgcn_s_sleep(2);
          }
          __syncthreads();
          __builtin_amdgcn_fence(__ATOMIC_ACQUIRE, "agent");
        }
        STAGE(gs);
        asm volatile("s_waitcnt vmcnt(18)" ::: "memory");  // chunk g landed; 3 chunks in flight
      } else if (gs == 1024) {
        asm volatile("s_waitcnt vmcnt(12)" ::: "memory");
      } else if (gs == 1025) {
        asm volatile("s_waitcnt vmcnt(6)" ::: "memory");
      } else {
        asm volatile("s_waitcnt vmcnt(0)" ::: "memory");
      }
      __builtin_amdgcn_s_barrier();

#pragma unroll
      for (int ks = 0; ks < 2; ++ks) {
        bf16x8 a[2], b[4];
        int sb = ks * 4 + l4;
#pragma unroll
        for (int mi = 0; mi < 2; ++mi) {
          int row = wr * 32 + mi * 16 + l15;
          a[mi] = *(const bf16x8*)(cur + row * 128 + (sb ^ (row & 7)) * 16);
        }
#pragma unroll
        for (int ni = 0; ni < 4; ++ni) {
          int row = wc * 64 + ni * 16 + l15;
          b[ni] = *(const bf16x8*)(cur + 8192 + row * 128 + (sb ^ (row & 7)) * 16);
        }
#pragma unroll
        for (int mi = 0; mi < 2; ++mi)
#pragma unroll
          for (int ni = 0; ni < 4; ++ni)
            acc[mi][ni] = __builtin_amdgcn_mfma_f32_16x16x32_bf16(a[mi], b[ni], acc[mi][ni], 0, 0, 0);
      }
    }

    // ---- step epilogue: gates + c/h update (sD is a separate LDS region) ----
#pragma unroll
    for (int mi = 0; mi < 2; ++mi)
#pragma unroll
      for (int ni = 0; ni < 4; ++ni) {
        int rowb = wr * 32 + mi * 16 + l4 * 4;
        int col = wc * 64 + ni * 16 + l15;
#pragma unroll
        for (int r = 0; r < 4; ++r) {
          int rr = rowb + r;
          sD[rr * 128 + (col ^ (((rr >> 2) & 3) << 4))] = acc[mi][ni][r];
        }
      }
    __syncthreads();

    const int t = dir ? 63 - s : s;
    unsigned short* hod = hs_my + (size_t)t * BH;
#pragma unroll
    for (int ii = 0; ii < 8; ++ii) {
      int row = r0 + ii * 8;
      int sw = ((row >> 2) & 3) << 4;
      float iv = sD[row * 128 + ((0  + hl) ^ sw)] + bi;
      float fv = sD[row * 128 + ((32 + hl) ^ sw)] + bff;
      float gv = sD[row * 128 + ((64 + hl) ^ sw)] + bg;
      float ov = sD[row * 128 + ((96 + hl) ^ sw)] + bo;
      float ig = sigm(iv);
      float fg = sigm(fv);
      float gg = tanh_f(gv);
      float og = sigm(ov);
      float cn = fg * cv[ii] + ig * gg;
      cv[ii] = cn;
      hod[(size_t)(b0 + row) * Hsz + hcg] = f2bf(og * tanh_f(cn));
    }
    __threadfence();      // agent-scope release of this wave's h stores
    __syncthreads();
    if (tid == 0)
      __hip_atomic_fetch_add(mybar, 1, __ATOMIC_RELEASE, __HIP_MEMORY_SCOPE_AGENT);

#pragma unroll
    for (int i = 0; i < 2; ++i)
#pragma unroll
      for (int j = 0; j < 4; ++j) acc[i][j] = z4;
  }
}

// ---------------- output GEMM: XCD-swizzled (round-6, kept) ----------------
__global__ __launch_bounds__(256) void k_out(
    const unsigned short* __restrict__ hsf, const unsigned short* __restrict__ hsb,
    const unsigned short* __restrict__ wlin, const float* __restrict__ blin,
    float* __restrict__ out) {
  extern __shared__ char smem[];
  const int tid = threadIdx.x;
  const int bidx = blockIdx.x;
  const int mt = (bidx & 7) + 8 * (bidx >> 5);
  const int nt = (bidx >> 3) & 3;
  const int m0 = mt * 128, n0 = nt * 128;
  const int lane = tid & 63, wv = tid >> 6;
  const int wr = wv >> 1, wc = wv & 1;
  const int l15 = lane & 15, l4 = lane >> 4;

  const f32x4 z4 = {0.f, 0.f, 0.f, 0.f};
  f32x4 acc[4][4];
#pragma unroll
  for (int i = 0; i < 4; ++i)
#pragma unroll
    for (int j = 0; j < 4; ++j) acc[i][j] = z4;

  for (int kc = 0; kc < 16; ++kc) {
    if (kc) __syncthreads();
    const unsigned short* Asrc = (kc < 8) ? hsf : hsb;
    const int kk = (kc & 7) * 64;
#pragma unroll
    for (int it = 0; it < 4; ++it) {
      int idx = it * 256 + tid;
      int row = idx >> 3, c16 = idx & 7;
      int sc = c16 ^ (row & 7);
      gload16(Asrc + (size_t)(m0 + row) * 512 + kk + sc * 8, smem + idx * 16);
    }
#pragma unroll
    for (int it = 0; it < 4; ++it) {
      int idx = it * 256 + tid;
      int row = idx >> 3, c16 = idx & 7;
      int sc = c16 ^ (row & 7);
      gload16(wlin + (size_t)(n0 + row) * 1024 + kc * 64 + sc * 8, smem + 16384 + idx * 16);
    }
    __syncthreads();
#pragma unroll
    for (int ks = 0; ks < 2; ++ks) {
      bf16x8 a[4], b[4];
      int sb = ks * 4 + l4;
#pragma unroll
      for (int mi = 0; mi < 4; ++mi) {
        int row = wr * 64 + mi * 16 + l15;
        a[mi] = *(const bf16x8*)(smem + row * 128 + (sb ^ (row & 7)) * 16);
      }
#pragma unroll
      for (int ni = 0; ni < 4; ++ni) {
        int row = wc * 64 + ni * 16 + l15;
        b[ni] = *(const bf16x8*)(smem + 16384 + row * 128 + (sb ^ (row & 7)) * 16);
      }
#pragma unroll
      for (int mi = 0; mi < 4; ++mi)
#pragma unroll
        for (int ni = 0; ni < 4; ++ni)
          acc[mi][ni] = __builtin_amdgcn_mfma_f32_16x16x32_bf16(a[mi], b[ni], acc[mi][ni], 0, 0, 0);
    }
  }
#pragma unroll
  for (int mi = 0; mi < 4; ++mi)
#pragma unroll
    for (int ni = 0; ni < 4; ++ni) {
      int cc = n0 + wc * 64 + ni * 16 + l15;
      float bl = blin[cc];
#pragma unroll
      for (int r = 0; r < 4; ++r) {
        int rr = m0 + wr * 64 + mi * 16 + l4 * 4 + r;
        int b = rr & 511, t = rr >> 9;
        out[(size_t)(b * 64 + t) * 512 + cc] = acc[mi][ni][r] + bl;
      }
    }
}

extern "C" void kernel_launch(void* const* d_in, const int* in_sizes, int n_in,
                              void* d_out, int out_size, void* d_ws, size_t ws_size,
                              hipStream_t stream) {
  const float* x     = (const float*)d_in[0];
  const float* wih_f = (const float*)d_in[1];
  const float* whh_f = (const float*)d_in[2];
  const float* b_f   = (const float*)d_in[3];
  const float* wih_b = (const float*)d_in[4];
  const float* whh_b = (const float*)d_in[5];
  const float* b_b   = (const float*)d_in[6];
  const float* wlin  = (const float*)d_in[7];
  const float* blin  = (const float*)d_in[8];
  float* out = (float*)d_out;

  char* ws = (char*)d_ws;
  unsigned short* Wcat   = (unsigned short*)(ws + 0);           // 8 MB
  unsigned short* wlinbf = (unsigned short*)(ws + 8388608);     // 1 MB
  unsigned short* xbf    = (unsigned short*)(ws + 9437184);     // 32 MB
  unsigned short* hsf    = (unsigned short*)(ws + 42991616);    // 32 MB
  unsigned short* hsb    = (unsigned short*)(ws + 76546048);    // 32 MB
  unsigned short* h0     = (unsigned short*)(ws + 110100480);   // 512 KB
  int*            bar    = (int*)(ws + 110624768);              // 64 B

  hipMemsetAsync(h0, 0, 524288, stream);
  hipMemsetAsync(bar, 0, 1024, stream);
  k_conv_x<<<8192, 256, 0, stream>>>(x, xbf);
  k_conv_w<<<2304, 256, 0, stream>>>(wih_f, whh_f, wih_b, whh_b, wlin, Wcat, wlinbf);

  {
    const unsigned short* a_xbf = xbf;
    const unsigned short* a_h0 = h0;
    const unsigned short* a_W = Wcat;
    const float* a_bf = b_f;
    const float* a_bb = b_b;
    unsigned short* a_hsf = hsf;
    unsigned short* a_hsb = hsb;
    int* a_bar = bar;
    void* args[] = {&a_xbf, &a_h0, &a_W, &a_bf, &a_bb, &a_hsf, &a_hsb, &a_bar};
    hipLaunchCooperativeKernel((void*)k_lstm, dim3(256), dim3(256), args, 155648, stream);
  }

  k_out<<<1024, 256, 32768, stream>>>(hsf, hsb, wlinbf, blin, out);
}

// Round 8
// 905.948 us; speedup vs baseline: 2.9916x; 2.9916x over previous
//
#include <hip/hip_runtime.h>

#define Bsz 512
#define Tsz 64
#define Hsz 512

typedef __attribute__((ext_vector_type(8))) short bf16x8;
typedef __attribute__((ext_vector_type(4))) float f32x4;

__device__ __forceinline__ unsigned short f2bf(float f) {
  union { float f; unsigned int u; } a; a.f = f;
  unsigned int u = a.u;
  unsigned int lsb = (u >> 16) & 1;
  u += 0x7fffu + lsb;   // round-to-nearest-even
  return (unsigned short)(u >> 16);
}

__device__ __forceinline__ void gload16(const void* g, void* l) {
  __builtin_amdgcn_global_load_lds(
      (const __attribute__((address_space(1))) unsigned int*)g,
      (__attribute__((address_space(3))) unsigned int*)l, 16, 0, 0);
}

__device__ __forceinline__ float sigm(float x) { return 1.f / (1.f + __expf(-x)); }
__device__ __forceinline__ float tanh_f(float x) { return 2.f / (1.f + __expf(-2.f * x)) - 1.f; }

// ---------------- converts ----------------
__global__ __launch_bounds__(256) void k_conv_x(const float* __restrict__ x,
                                                unsigned short* __restrict__ xbf) {
  int v = blockIdx.x * 256 + threadIdx.x;
  int e = v * 8;
  int i = e & 511;
  int t = (e >> 9) & 63;
  int b = e >> 15;
  float4 f0 = *(const float4*)(x + e);
  float4 f1 = *(const float4*)(x + e + 4);
  bf16x8 o;
  o[0] = (short)f2bf(f0.x); o[1] = (short)f2bf(f0.y);
  o[2] = (short)f2bf(f0.z); o[3] = (short)f2bf(f0.w);
  o[4] = (short)f2bf(f1.x); o[5] = (short)f2bf(f1.y);
  o[6] = (short)f2bf(f1.z); o[7] = (short)f2bf(f1.w);
  *(bf16x8*)(xbf + ((size_t)(t * 512 + b) << 9) + i) = o;
}

__global__ __launch_bounds__(256) void k_conv_w(
    const float* __restrict__ wihf, const float* __restrict__ whhf,
    const float* __restrict__ wihb, const float* __restrict__ whhb,
    const float* __restrict__ wlin,
    unsigned short* __restrict__ Wcat, unsigned short* __restrict__ wlinbf) {
  int v = blockIdx.x * 256 + threadIdx.x;
  const int nW = 2 * 16 * 128 * 128;
  if (v < nW) {
    int k8 = v & 127; int row = v >> 7;
    int c = row & 127, sl = (row >> 7) & 15, d = row >> 11;
    int g = c >> 5, hl = c & 31;
    int wr = g * 512 + sl * 32 + hl;
    int k = k8 * 8;
    const float* src;
    if (k < 512) src = (d ? wihb : wihf) + (size_t)wr * 512 + k;
    else         src = (d ? whhb : whhf) + (size_t)wr * 512 + (k - 512);
    float4 f0 = *(const float4*)src;
    float4 f1 = *(const float4*)(src + 4);
    bf16x8 o;
    o[0] = (short)f2bf(f0.x); o[1] = (short)f2bf(f0.y);
    o[2] = (short)f2bf(f0.z); o[3] = (short)f2bf(f0.w);
    o[4] = (short)f2bf(f1.x); o[5] = (short)f2bf(f1.y);
    o[6] = (short)f2bf(f1.z); o[7] = (short)f2bf(f1.w);
    *(bf16x8*)(Wcat + (size_t)row * 1024 + k) = o;
  } else {
    int v2 = v - nW;
    const float* src = wlin + (size_t)v2 * 8;
    float4 f0 = *(const float4*)src;
    float4 f1 = *(const float4*)(src + 4);
    bf16x8 o;
    o[0] = (short)f2bf(f0.x); o[1] = (short)f2bf(f0.y);
    o[2] = (short)f2bf(f0.z); o[3] = (short)f2bf(f0.w);
    o[4] = (short)f2bf(f1.x); o[5] = (short)f2bf(f1.y);
    o[6] = (short)f2bf(f1.z); o[7] = (short)f2bf(f1.w);
    *(bf16x8*)(wlinbf + (size_t)v2 * 8) = o;
  }
}

// ---------------- LSTM step: [32 batch][128 cols] tiles, 512 blocks (2/CU), XCD-local x/h ----
// bid decode: u=bid&7 (XCD), mt = u + 8*((bid>>3)&1) (0..15, 32-row tiles), cs = bid>>4 (0..31),
// dir = cs&1, sl = cs>>1. All 32 col-blocks of one mt share the XCD -> x/h slices L2-local.
// K=1024, BK=64, 16 chunks; buf = A[32][64](4KB)+B[128][64](16KB)=20KB; 4 bufs=80KB (2 blocks/CU).
// Stage depth 2, counted vmcnt(10), 1 barrier/chunk (write of buf[(m+2)&3] is barrier(m-1)-
// separated from its last read at iter m-2). Epilogue sD f32[32][128] reuses buf0.
__global__ __launch_bounds__(256) void k_step(
    const unsigned short* __restrict__ xf, const unsigned short* __restrict__ xb,
    const unsigned short* __restrict__ hpf, const unsigned short* __restrict__ hpb,
    const unsigned short* __restrict__ Wcat,
    const float* __restrict__ biasf, const float* __restrict__ biasb,
    float* __restrict__ c_all,
    unsigned short* __restrict__ hof, unsigned short* __restrict__ hob) {
  extern __shared__ char smem[];
  const int tid = threadIdx.x;
  const int bid = blockIdx.x;
  const int mt  = (bid & 7) + 8 * ((bid >> 3) & 1);
  const int cs  = bid >> 4;
  const int dir = cs & 1;
  const int sl  = cs >> 1;
  const int b0  = mt * 32;

  const unsigned short* xd = dir ? xb : xf;
  const unsigned short* hd = dir ? hpb : hpf;
  const unsigned short* Wd = Wcat + (size_t)(dir * 16 + sl) * (128 * 1024);
  const float* bias = dir ? biasb : biasf;
  float* cd = c_all + (size_t)dir * (Bsz * Hsz);
  unsigned short* hod = dir ? hob : hof;

  const int lane = tid & 63;
  const int wv = tid >> 6;               // wave 0..3 -> col group wv*32
  const int l15 = lane & 15, l4 = lane >> 4;

  // early loads (drain under the GEMM): c state + biases
  const int hl = tid & 31;
  const int r0 = tid >> 5;               // 0..7
  const int hcg = sl * 32 + hl;
  float cv[4];
#pragma unroll
  for (int ii = 0; ii < 4; ++ii)
    cv[ii] = cd[(size_t)(b0 + r0 + ii * 8) * Hsz + hcg];
  const float bi = bias[hcg], bff = bias[512 + hcg], bg = bias[1024 + hcg], bo = bias[1536 + hcg];

  const f32x4 z4 = {0.f, 0.f, 0.f, 0.f};
  f32x4 acc[2][2];
#pragma unroll
  for (int i = 0; i < 2; ++i)
#pragma unroll
    for (int j = 0; j < 2; ++j) acc[i][j] = z4;

  // stage chunk kc: A 1 load/thread, B 4 loads/thread = 5
  auto STAGE = [&](int kc, char* buf) {
    const unsigned short* Asrc = (kc < 8) ? xd : hd;
    const int koff = (kc & 7) * 64;
    {
      int row = tid >> 3, g = tid & 7;   // 32 rows x 8 groups
      int sc = g ^ (row & 7);
      gload16(Asrc + (size_t)(b0 + row) * 512 + koff + sc * 8, buf + tid * 16);
    }
#pragma unroll
    for (int it = 0; it < 4; ++it) {
      int idx = it * 256 + tid;
      int row = idx >> 3, g = idx & 7;   // 128 rows x 8 groups
      int sc = g ^ (row & 7);
      gload16(Wd + (size_t)row * 1024 + kc * 64 + sc * 8, buf + 4096 + idx * 16);
    }
  };

  STAGE(0, smem);
  STAGE(1, smem + 20480);

  for (int m = 0; m < 16; ++m) {
    char* cur = smem + (m & 3) * 20480;
    if (m < 14) {
      STAGE(m + 2, smem + ((m + 2) & 3) * 20480);
      asm volatile("s_waitcnt vmcnt(10)" ::: "memory");  // chunk m landed; m+1,m+2 in flight
    } else if (m == 14) {
      asm volatile("s_waitcnt vmcnt(5)" ::: "memory");
    } else {
      asm volatile("s_waitcnt vmcnt(0)" ::: "memory");
    }
    __builtin_amdgcn_s_barrier();

#pragma unroll
    for (int ks = 0; ks < 2; ++ks) {
      bf16x8 a[2], b[2];
      int sb = ks * 4 + l4;
#pragma unroll
      for (int mi = 0; mi < 2; ++mi) {
        int row = mi * 16 + l15;
        a[mi] = *(const bf16x8*)(cur + row * 128 + (sb ^ (row & 7)) * 16);
      }
#pragma unroll
      for (int ni = 0; ni < 2; ++ni) {
        int row = wv * 32 + ni * 16 + l15;
        b[ni] = *(const bf16x8*)(cur + 4096 + row * 128 + (sb ^ (row & 7)) * 16);
      }
#pragma unroll
      for (int mi = 0; mi < 2; ++mi)
#pragma unroll
        for (int ni = 0; ni < 2; ++ni)
          acc[mi][ni] = __builtin_amdgcn_mfma_f32_16x16x32_bf16(a[mi], b[ni], acc[mi][ni], 0, 0, 0);
    }
  }
  __syncthreads();

  // dump acc -> sD [32][128] f32, bank-swizzled: col ^= ((row>>2)&3)<<4
  float* sD = (float*)smem;
#pragma unroll
  for (int mi = 0; mi < 2; ++mi)
#pragma unroll
    for (int ni = 0; ni < 2; ++ni) {
      int rowb = mi * 16 + l4 * 4;
      int col = wv * 32 + ni * 16 + l15;
#pragma unroll
      for (int r = 0; r < 4; ++r) {
        int rr = rowb + r;
        sD[rr * 128 + (col ^ (((rr >> 2) & 3) << 4))] = acc[mi][ni][r];
      }
    }
  __syncthreads();

#pragma unroll
  for (int ii = 0; ii < 4; ++ii) {
    int row = r0 + ii * 8;
    int sw = ((row >> 2) & 3) << 4;
    float iv = sD[row * 128 + ((0  + hl) ^ sw)] + bi;
    float fv = sD[row * 128 + ((32 + hl) ^ sw)] + bff;
    float gv = sD[row * 128 + ((64 + hl) ^ sw)] + bg;
    float ov = sD[row * 128 + ((96 + hl) ^ sw)] + bo;
    float ig = sigm(iv);
    float fg = sigm(fv);
    float gg = tanh_f(gv);
    float og = sigm(ov);
    size_t gi = (size_t)(b0 + row) * Hsz + hcg;
    float cn = fg * cv[ii] + ig * gg;
    cd[gi] = cn;
    hod[gi] = f2bf(og * tanh_f(cn));
  }
}

// ---------------- output GEMM: XCD-swizzled (round-6, kept) ----------------
__global__ __launch_bounds__(256) void k_out(
    const unsigned short* __restrict__ hsf, const unsigned short* __restrict__ hsb,
    const unsigned short* __restrict__ wlin, const float* __restrict__ blin,
    float* __restrict__ out) {
  extern __shared__ char smem[];
  const int tid = threadIdx.x;
  const int bidx = blockIdx.x;
  const int mt = (bidx & 7) + 8 * (bidx >> 5);
  const int nt = (bidx >> 3) & 3;
  const int m0 = mt * 128, n0 = nt * 128;
  const int lane = tid & 63, wv = tid >> 6;
  const int wr = wv >> 1, wc = wv & 1;
  const int l15 = lane & 15, l4 = lane >> 4;

  const f32x4 z4 = {0.f, 0.f, 0.f, 0.f};
  f32x4 acc[4][4];
#pragma unroll
  for (int i = 0; i < 4; ++i)
#pragma unroll
    for (int j = 0; j < 4; ++j) acc[i][j] = z4;

  for (int kc = 0; kc < 16; ++kc) {
    if (kc) __syncthreads();
    const unsigned short* Asrc = (kc < 8) ? hsf : hsb;
    const int kk = (kc & 7) * 64;
#pragma unroll
    for (int it = 0; it < 4; ++it) {
      int idx = it * 256 + tid;
      int row = idx >> 3, c16 = idx & 7;
      int sc = c16 ^ (row & 7);
      gload16(Asrc + (size_t)(m0 + row) * 512 + kk + sc * 8, smem + idx * 16);
    }
#pragma unroll
    for (int it = 0; it < 4; ++it) {
      int idx = it * 256 + tid;
      int row = idx >> 3, c16 = idx & 7;
      int sc = c16 ^ (row & 7);
      gload16(wlin + (size_t)(n0 + row) * 1024 + kc * 64 + sc * 8, smem + 16384 + idx * 16);
    }
    __syncthreads();
#pragma unroll
    for (int ks = 0; ks < 2; ++ks) {
      bf16x8 a[4], b[4];
      int sb = ks * 4 + l4;
#pragma unroll
      for (int mi = 0; mi < 4; ++mi) {
        int row = wr * 64 + mi * 16 + l15;
        a[mi] = *(const bf16x8*)(smem + row * 128 + (sb ^ (row & 7)) * 16);
      }
#pragma unroll
      for (int ni = 0; ni < 4; ++ni) {
        int row = wc * 64 + ni * 16 + l15;
        b[ni] = *(const bf16x8*)(smem + 16384 + row * 128 + (sb ^ (row & 7)) * 16);
      }
#pragma unroll
      for (int mi = 0; mi < 4; ++mi)
#pragma unroll
        for (int ni = 0; ni < 4; ++ni)
          acc[mi][ni] = __builtin_amdgcn_mfma_f32_16x16x32_bf16(a[mi], b[ni], acc[mi][ni], 0, 0, 0);
    }
  }
#pragma unroll
  for (int mi = 0; mi < 4; ++mi)
#pragma unroll
    for (int ni = 0; ni < 4; ++ni) {
      int cc = n0 + wc * 64 + ni * 16 + l15;
      float bl = blin[cc];
#pragma unroll
      for (int r = 0; r < 4; ++r) {
        int rr = m0 + wr * 64 + mi * 16 + l4 * 4 + r;
        int b = rr & 511, t = rr >> 9;
        out[(size_t)(b * 64 + t) * 512 + cc] = acc[mi][ni][r] + bl;
      }
    }
}

extern "C" void kernel_launch(void* const* d_in, const int* in_sizes, int n_in,
                              void* d_out, int out_size, void* d_ws, size_t ws_size,
                              hipStream_t stream) {
  const float* x     = (const float*)d_in[0];
  const float* wih_f = (const float*)d_in[1];
  const float* whh_f = (const float*)d_in[2];
  const float* b_f   = (const float*)d_in[3];
  const float* wih_b = (const float*)d_in[4];
  const float* whh_b = (const float*)d_in[5];
  const float* b_b   = (const float*)d_in[6];
  const float* wlin  = (const float*)d_in[7];
  const float* blin  = (const float*)d_in[8];
  float* out = (float*)d_out;

  char* ws = (char*)d_ws;
  unsigned short* Wcat   = (unsigned short*)(ws + 0);
  unsigned short* wlinbf = (unsigned short*)(ws + 8388608);
  unsigned short* xbf    = (unsigned short*)(ws + 9437184);
  unsigned short* hsf    = (unsigned short*)(ws + 42991616);
  unsigned short* hsb    = (unsigned short*)(ws + 76546048);
  float*          c_all  = (float*)(ws + 110100480);
  unsigned short* h0     = (unsigned short*)(ws + 112197632);

  hipMemsetAsync(c_all, 0, 2097152, stream);
  hipMemsetAsync(h0, 0, 524288, stream);
  k_conv_x<<<8192, 256, 0, stream>>>(x, xbf);
  k_conv_w<<<2304, 256, 0, stream>>>(wih_f, whh_f, wih_b, whh_b, wlin, Wcat, wlinbf);

  const size_t BH = (size_t)Bsz * Hsz;
  for (int s = 0; s < 64; ++s) {
    int tf = s, tb = 63 - s;
    const unsigned short* xfp = xbf + (size_t)tf * BH;
    const unsigned short* xbp = xbf + (size_t)tb * BH;
    const unsigned short* hpf = s ? hsf + (size_t)(tf - 1) * BH : h0;
    const unsigned short* hpb = s ? hsb + (size_t)(tb + 1) * BH : h0;
    k_step<<<512, 256, 81920, stream>>>(xfp, xbp, hpf, hpb, Wcat, b_f, b_b,
                                        c_all, hsf + (size_t)tf * BH, hsb + (size_t)tb * BH);
  }
  k_out<<<1024, 256, 32768, stream>>>(hsf, hsb, wlinbf, blin, out);
}

// Round 9
// 621.214 us; speedup vs baseline: 4.3629x; 1.4583x over previous
//
#include <hip/hip_runtime.h>

#define Bsz 512
#define Tsz 64
#define Hsz 512

typedef __attribute__((ext_vector_type(8))) short bf16x8;
typedef __attribute__((ext_vector_type(4))) float f32x4;

__device__ __forceinline__ unsigned short f2bf(float f) {
  union { float f; unsigned int u; } a; a.f = f;
  unsigned int u = a.u;
  unsigned int lsb = (u >> 16) & 1;
  u += 0x7fffu + lsb;   // round-to-nearest-even
  return (unsigned short)(u >> 16);
}

__device__ __forceinline__ void gload16(const void* g, void* l) {
  __builtin_amdgcn_global_load_lds(
      (const __attribute__((address_space(1))) unsigned int*)g,
      (__attribute__((address_space(3))) unsigned int*)l, 16, 0, 0);
}

__device__ __forceinline__ float sigm(float x) { return 1.f / (1.f + __expf(-x)); }
__device__ __forceinline__ float tanh_f(float x) { return 2.f / (1.f + __expf(-2.f * x)) - 1.f; }

// ---------------- converts ----------------
__global__ __launch_bounds__(256) void k_conv_x(const float* __restrict__ x,
                                                unsigned short* __restrict__ xbf) {
  int v = blockIdx.x * 256 + threadIdx.x;
  int e = v * 8;
  int i = e & 511;
  int t = (e >> 9) & 63;
  int b = e >> 15;
  float4 f0 = *(const float4*)(x + e);
  float4 f1 = *(const float4*)(x + e + 4);
  bf16x8 o;
  o[0] = (short)f2bf(f0.x); o[1] = (short)f2bf(f0.y);
  o[2] = (short)f2bf(f0.z); o[3] = (short)f2bf(f0.w);
  o[4] = (short)f2bf(f1.x); o[5] = (short)f2bf(f1.y);
  o[6] = (short)f2bf(f1.z); o[7] = (short)f2bf(f1.w);
  *(bf16x8*)(xbf + ((size_t)(t * 512 + b) << 9) + i) = o;
}

__global__ __launch_bounds__(256) void k_conv_w(
    const float* __restrict__ wihf, const float* __restrict__ whhf,
    const float* __restrict__ wihb, const float* __restrict__ whhb,
    const float* __restrict__ wlin,
    unsigned short* __restrict__ Wcat, unsigned short* __restrict__ wlinbf) {
  int v = blockIdx.x * 256 + threadIdx.x;
  const int nW = 2 * 16 * 128 * 128;
  if (v < nW) {
    int k8 = v & 127; int row = v >> 7;
    int c = row & 127, sl = (row >> 7) & 15, d = row >> 11;
    int g = c >> 5, hl = c & 31;
    int wr = g * 512 + sl * 32 + hl;
    int k = k8 * 8;
    const float* src;
    if (k < 512) src = (d ? wihb : wihf) + (size_t)wr * 512 + k;
    else         src = (d ? whhb : whhf) + (size_t)wr * 512 + (k - 512);
    float4 f0 = *(const float4*)src;
    float4 f1 = *(const float4*)(src + 4);
    bf16x8 o;
    o[0] = (short)f2bf(f0.x); o[1] = (short)f2bf(f0.y);
    o[2] = (short)f2bf(f0.z); o[3] = (short)f2bf(f0.w);
    o[4] = (short)f2bf(f1.x); o[5] = (short)f2bf(f1.y);
    o[6] = (short)f2bf(f1.z); o[7] = (short)f2bf(f1.w);
    *(bf16x8*)(Wcat + (size_t)row * 1024 + k) = o;
  } else {
    int v2 = v - nW;
    const float* src = wlin + (size_t)v2 * 8;
    float4 f0 = *(const float4*)src;
    float4 f1 = *(const float4*)(src + 4);
    bf16x8 o;
    o[0] = (short)f2bf(f0.x); o[1] = (short)f2bf(f0.y);
    o[2] = (short)f2bf(f0.z); o[3] = (short)f2bf(f0.w);
    o[4] = (short)f2bf(f1.x); o[5] = (short)f2bf(f1.y);
    o[6] = (short)f2bf(f1.z); o[7] = (short)f2bf(f1.w);
    *(bf16x8*)(wlinbf + (size_t)v2 * 8) = o;
  }
}

// ---------------- LSTM step: 8 waves (2/SIMD TLP), same bytes as R6 ----------------
// grid 256 (1 block/CU): blockIdx = mt*32 + sl*2 + dir; tile [64 batch][128 cols], K=1024,
// BK=64 (16 chunks). buf = A[64][64](8KB)+B[128][64](16KB)=24KB; 5 bufs=120KB; depth-3,
// counted vmcnt(9) (3 gload16/thread/STAGE at 512 threads). 8 waves as 2(wr)x4(wc), 32x32 acc.
// Epilogue sD f32[64][128]=32KB reuses buf0+. XCD map: bid%8 = cs%8 -> W slices L2-resident.
__global__ __launch_bounds__(512) void k_step(
    const unsigned short* __restrict__ xf, const unsigned short* __restrict__ xb,
    const unsigned short* __restrict__ hpf, const unsigned short* __restrict__ hpb,
    const unsigned short* __restrict__ Wcat,
    const float* __restrict__ biasf, const float* __restrict__ biasb,
    float* __restrict__ c_all,
    unsigned short* __restrict__ hof, unsigned short* __restrict__ hob) {
  extern __shared__ char smem[];
  const int tid = threadIdx.x;
  const int g32 = blockIdx.x & 31;
  const int mt  = blockIdx.x >> 5;
  const int dir = g32 & 1;
  const int sl  = g32 >> 1;
  const int b0  = mt * 64;

  const unsigned short* xd = dir ? xb : xf;
  const unsigned short* hd = dir ? hpb : hpf;
  const unsigned short* Wd = Wcat + (size_t)(dir * 16 + sl) * (128 * 1024);
  const float* bias = dir ? biasb : biasf;
  float* cd = c_all + (size_t)dir * (Bsz * Hsz);
  unsigned short* hod = dir ? hob : hof;

  const int lane = tid & 63;
  const int wv = tid >> 6;               // 0..7
  const int wr = wv >> 2, wc = wv & 3;   // 2 x 4
  const int l15 = lane & 15, l4 = lane >> 4;

  // early loads (oldest in vmcnt order; drained by the first counted wait)
  const int hl = tid & 31;
  const int r0 = tid >> 5;               // 0..15
  const int hcg = sl * 32 + hl;
  float cv[4];
#pragma unroll
  for (int ii = 0; ii < 4; ++ii)
    cv[ii] = cd[(size_t)(b0 + r0 + ii * 16) * Hsz + hcg];
  const float bi = bias[hcg], bff = bias[512 + hcg], bg = bias[1024 + hcg], bo = bias[1536 + hcg];

  const f32x4 z4 = {0.f, 0.f, 0.f, 0.f};
  f32x4 acc[2][2];
#pragma unroll
  for (int i = 0; i < 2; ++i)
#pragma unroll
    for (int j = 0; j < 2; ++j) acc[i][j] = z4;

  // stage chunk kc: A 1 gload/thread (512 chunks), B 2 gloads/thread (1024 chunks)
  auto STAGE = [&](int kc, char* buf) {
    const unsigned short* Asrc = (kc < 8) ? xd : hd;
    const int koff = (kc & 7) * 64;
    {
      int row = tid >> 3, g = tid & 7;           // 64 rows x 8 groups
      int sc = g ^ (row & 7);
      gload16(Asrc + (size_t)(b0 + row) * 512 + koff + sc * 8, buf + tid * 16);
    }
#pragma unroll
    for (int it = 0; it < 2; ++it) {
      int idx = it * 512 + tid;
      int row = idx >> 3, g = idx & 7;           // 128 rows x 8 groups
      int sc = g ^ (row & 7);
      gload16(Wd + (size_t)row * 1024 + kc * 64 + sc * 8, buf + 8192 + idx * 16);
    }
  };

  STAGE(0, smem);
  STAGE(1, smem + 24576);
  STAGE(2, smem + 49152);

  for (int m = 0; m < 16; ++m) {
    char* cur = smem + (m % 5) * 24576;
    if (m < 13) {
      STAGE(m + 3, smem + ((m + 3) % 5) * 24576);
      asm volatile("s_waitcnt vmcnt(9)" ::: "memory");   // chunk m landed; m+1..m+3 in flight
    } else if (m == 13) {
      asm volatile("s_waitcnt vmcnt(6)" ::: "memory");
    } else if (m == 14) {
      asm volatile("s_waitcnt vmcnt(3)" ::: "memory");
    } else {
      asm volatile("s_waitcnt vmcnt(0)" ::: "memory");
    }
    __builtin_amdgcn_s_barrier();

#pragma unroll
    for (int ks = 0; ks < 2; ++ks) {
      bf16x8 a[2], b[2];
      int sb = ks * 4 + l4;
#pragma unroll
      for (int mi = 0; mi < 2; ++mi) {
        int row = wr * 32 + mi * 16 + l15;
        a[mi] = *(const bf16x8*)(cur + row * 128 + (sb ^ (row & 7)) * 16);
      }
#pragma unroll
      for (int ni = 0; ni < 2; ++ni) {
        int row = wc * 32 + ni * 16 + l15;
        b[ni] = *(const bf16x8*)(cur + 8192 + row * 128 + (sb ^ (row & 7)) * 16);
      }
#pragma unroll
      for (int mi = 0; mi < 2; ++mi)
#pragma unroll
        for (int ni = 0; ni < 2; ++ni)
          acc[mi][ni] = __builtin_amdgcn_mfma_f32_16x16x32_bf16(a[mi], b[ni], acc[mi][ni], 0, 0, 0);
    }
    // single barrier per chunk: buf[(m+3)%5] written at iter m was last read at iter m-2,
    // and those reads are consumed before each wave passed barrier(m-1).
  }
  __syncthreads();

  // dump acc -> sD [64][128] f32, bank-swizzled: col ^= ((row>>2)&3)<<4
  float* sD = (float*)smem;
#pragma unroll
  for (int mi = 0; mi < 2; ++mi)
#pragma unroll
    for (int ni = 0; ni < 2; ++ni) {
      int rowb = wr * 32 + mi * 16 + l4 * 4;
      int col = wc * 32 + ni * 16 + l15;
#pragma unroll
      for (int r = 0; r < 4; ++r) {
        int rr = rowb + r;
        sD[rr * 128 + (col ^ (((rr >> 2) & 3) << 4))] = acc[mi][ni][r];
      }
    }
  __syncthreads();

#pragma unroll
  for (int ii = 0; ii < 4; ++ii) {
    int row = r0 + ii * 16;
    int sw = ((row >> 2) & 3) << 4;
    float iv = sD[row * 128 + ((0  + hl) ^ sw)] + bi;
    float fv = sD[row * 128 + ((32 + hl) ^ sw)] + bff;
    float gv = sD[row * 128 + ((64 + hl) ^ sw)] + bg;
    float ov = sD[row * 128 + ((96 + hl) ^ sw)] + bo;
    float ig = sigm(iv);
    float fg = sigm(fv);
    float gg = tanh_f(gv);
    float og = sigm(ov);
    size_t gi = (size_t)(b0 + row) * Hsz + hcg;
    float cn = fg * cv[ii] + ig * gg;
    cd[gi] = cn;
    hod[gi] = f2bf(og * tanh_f(cn));
  }
}

// ---------------- output GEMM: XCD-swizzled (unchanged) ----------------
__global__ __launch_bounds__(256) void k_out(
    const unsigned short* __restrict__ hsf, const unsigned short* __restrict__ hsb,
    const unsigned short* __restrict__ wlin, const float* __restrict__ blin,
    float* __restrict__ out) {
  extern __shared__ char smem[];
  const int tid = threadIdx.x;
  const int bidx = blockIdx.x;
  const int mt = (bidx & 7) + 8 * (bidx >> 5);
  const int nt = (bidx >> 3) & 3;
  const int m0 = mt * 128, n0 = nt * 128;
  const int lane = tid & 63, wv = tid >> 6;
  const int wr = wv >> 1, wc = wv & 1;
  const int l15 = lane & 15, l4 = lane >> 4;

  const f32x4 z4 = {0.f, 0.f, 0.f, 0.f};
  f32x4 acc[4][4];
#pragma unroll
  for (int i = 0; i < 4; ++i)
#pragma unroll
    for (int j = 0; j < 4; ++j) acc[i][j] = z4;

  for (int kc = 0; kc < 16; ++kc) {
    if (kc) __syncthreads();
    const unsigned short* Asrc = (kc < 8) ? hsf : hsb;
    const int kk = (kc & 7) * 64;
#pragma unroll
    for (int it = 0; it < 4; ++it) {
      int idx = it * 256 + tid;
      int row = idx >> 3, c16 = idx & 7;
      int sc = c16 ^ (row & 7);
      gload16(Asrc + (size_t)(m0 + row) * 512 + kk + sc * 8, smem + idx * 16);
    }
#pragma unroll
    for (int it = 0; it < 4; ++it) {
      int idx = it * 256 + tid;
      int row = idx >> 3, c16 = idx & 7;
      int sc = c16 ^ (row & 7);
      gload16(wlin + (size_t)(n0 + row) * 1024 + kc * 64 + sc * 8, smem + 16384 + idx * 16);
    }
    __syncthreads();
#pragma unroll
    for (int ks = 0; ks < 2; ++ks) {
      bf16x8 a[4], b[4];
      int sb = ks * 4 + l4;
#pragma unroll
      for (int mi = 0; mi < 4; ++mi) {
        int row = wr * 64 + mi * 16 + l15;
        a[mi] = *(const bf16x8*)(smem + row * 128 + (sb ^ (row & 7)) * 16);
      }
#pragma unroll
      for (int ni = 0; ni < 4; ++ni) {
        int row = wc * 64 + ni * 16 + l15;
        b[ni] = *(const bf16x8*)(smem + 16384 + row * 128 + (sb ^ (row & 7)) * 16);
      }
#pragma unroll
      for (int mi = 0; mi < 4; ++mi)
#pragma unroll
        for (int ni = 0; ni < 4; ++ni)
          acc[mi][ni] = __builtin_amdgcn_mfma_f32_16x16x32_bf16(a[mi], b[ni], acc[mi][ni], 0, 0, 0);
    }
  }
#pragma unroll
  for (int mi = 0; mi < 4; ++mi)
#pragma unroll
    for (int ni = 0; ni < 4; ++ni) {
      int cc = n0 + wc * 64 + ni * 16 + l15;
      float bl = blin[cc];
#pragma unroll
      for (int r = 0; r < 4; ++r) {
        int rr = m0 + wr * 64 + mi * 16 + l4 * 4 + r;
        int b = rr & 511, t = rr >> 9;
        out[(size_t)(b * 64 + t) * 512 + cc] = acc[mi][ni][r] + bl;
      }
    }
}

extern "C" void kernel_launch(void* const* d_in, const int* in_sizes, int n_in,
                              void* d_out, int out_size, void* d_ws, size_t ws_size,
                              hipStream_t stream) {
  const float* x     = (const float*)d_in[0];
  const float* wih_f = (const float*)d_in[1];
  const float* whh_f = (const float*)d_in[2];
  const float* b_f   = (const float*)d_in[3];
  const float* wih_b = (const float*)d_in[4];
  const float* whh_b = (const float*)d_in[5];
  const float* b_b   = (const float*)d_in[6];
  const float* wlin  = (const float*)d_in[7];
  const float* blin  = (const float*)d_in[8];
  float* out = (float*)d_out;

  char* ws = (char*)d_ws;
  unsigned short* Wcat   = (unsigned short*)(ws + 0);
  unsigned short* wlinbf = (unsigned short*)(ws + 8388608);
  unsigned short* xbf    = (unsigned short*)(ws + 9437184);
  unsigned short* hsf    = (unsigned short*)(ws + 42991616);
  unsigned short* hsb    = (unsigned short*)(ws + 76546048);
  float*          c_all  = (float*)(ws + 110100480);
  unsigned short* h0     = (unsigned short*)(ws + 112197632);

  hipMemsetAsync(c_all, 0, 2097152, stream);
  hipMemsetAsync(h0, 0, 524288, stream);
  k_conv_x<<<8192, 256, 0, stream>>>(x, xbf);
  k_conv_w<<<2304, 256, 0, stream>>>(wih_f, whh_f, wih_b, whh_b, wlin, Wcat, wlinbf);

  const size_t BH = (size_t)Bsz * Hsz;
  for (int s = 0; s < 64; ++s) {
    int tf = s, tb = 63 - s;
    const unsigned short* xfp = xbf + (size_t)tf * BH;
    const unsigned short* xbp = xbf + (size_t)tb * BH;
    const unsigned short* hpf = s ? hsf + (size_t)(tf - 1) * BH : h0;
    const unsigned short* hpb = s ? hsb + (size_t)(tb + 1) * BH : h0;
    k_step<<<256, 512, 122880, stream>>>(xfp, xbp, hpf, hpb, Wcat, b_f, b_b,
                                         c_all, hsf + (size_t)tf * BH, hsb + (size_t)tb * BH);
  }
  k_out<<<1024, 256, 32768, stream>>>(hsf, hsb, wlinbf, blin, out);
}